// Round 2
// baseline (205.354 us; speedup 1.0000x reference)
//
#include <hip/hip_runtime.h>
#include <math.h>

#define EPS 0.3f
#define CAP 64          // fixed per-node edge capacity (Poisson(16): P(deg>64) ~ 1e-18)
#define SPILLCAP 65536  // safety spill list (never used on this input)

typedef __attribute__((ext_vector_type(8))) short bf16x8;
typedef __attribute__((ext_vector_type(4))) float f32x4;

__device__ __forceinline__ short f2bf(float f) {
    union { float f; unsigned u; } v; v.f = f;
    unsigned r = v.u + 0x7FFFu + ((v.u >> 16) & 1u);  // RNE
    return (short)(r >> 16);
}
__device__ __forceinline__ float bf2f(short s) {
    union { unsigned u; float f; } v;
    v.u = ((unsigned)(unsigned short)s) << 16;
    return v.f;
}
// pack two fp32 -> 2x bf16 in one int (low = first arg)
__device__ __forceinline__ int f2bf_pk(float lo, float hi) {
#if __has_builtin(__builtin_amdgcn_cvt_pk_bf16_f32)
    auto r = __builtin_amdgcn_cvt_pk_bf16_f32(lo, hi);
    int out; __builtin_memcpy(&out, &r, 4);
    return out;
#else
    return ((int)(unsigned short)f2bf(lo)) | (((int)(unsigned short)f2bf(hi)) << 16);
#endif
}
// tanh via HW exp: 1 - 2/(1+e^{2x}); saturates correctly, ~1e-6 rel err.
__device__ __forceinline__ float fast_tanh(float x) {
    return 1.0f - 2.0f / (1.0f + __expf(2.0f * x));
}

// ---- R18: CSR build replaced by fixed-capacity bucket scatter ----
// Old: hist -> scan -> partition -> bin_csr (4 serial stages, 2 full edge
// passes + single-block scan). New: one atomic scatter into 64-slot/node
// buckets; deg comes from cnt[]; d=rsqrt(deg) computed in gather preamble.
// Scatter has NO dependency on t1, so they share one launch (block-split).

// K1: init — w fp32->bf16 conversion, cnt zero, spillN zero
__global__ __launch_bounds__(256) void init_k(const float* __restrict__ w,
                                              short* __restrict__ wb,
                                              int* __restrict__ cnt,
                                              int* __restrict__ spillN, int N) {
    int bid = blockIdx.x, tid = threadIdx.x;
    if (bid < 64) wb[bid * 256 + tid] = f2bf(w[bid * 256 + tid]);
    for (int i = bid * 256 + tid; i < N; i += gridDim.x * 256) cnt[i] = 0;
    if (bid == 0 && tid == 0) *spillN = 0;
}

// K2: blocks [0,SCB): edge scatter; blocks [SCB,...): t1 MFMA path.
// x0 = relu(h @ w^T + b) in bf16; fused layer-0 gate dots.
// MFMA 16x16x32 bf16. A: [m=lane&15][k=quad*8+j]; D: col=lane&15, row=quad*4+reg.
#define LROW 264   // LDS row stride in shorts (256 + 8 pad): 528 B
__global__ __launch_bounds__(256) void scatter_t1(
    const int* __restrict__ src, const int* __restrict__ dst, int E,
    int* __restrict__ cnt, unsigned short* __restrict__ esrc2,
    unsigned* __restrict__ spill, int* __restrict__ spillN,
    const float* __restrict__ h, const short* __restrict__ wb,
    const float* __restrict__ t1b, const float* __restrict__ gw,
    short* __restrict__ XAh, float* __restrict__ ga0, float* __restrict__ gb0,
    int N, int SCB)
{
    __shared__ short lds[4][16 * LROW];
    int tid = threadIdx.x;

    if ((int)blockIdx.x < SCB) {
        // ---- scatter path: bucket edges by dst ----
        for (int i = blockIdx.x * 256 + tid; i < E; i += SCB * 256) {
            int d = dst[i];
            int slot = atomicAdd(&cnt[d], 1);
            if (slot < CAP) {
                esrc2[(size_t)d * CAP + slot] = (unsigned short)src[i];
            } else {
                int sp = atomicAdd(spillN, 1);
                if (sp < SPILLCAP)
                    spill[sp] = ((unsigned)d << 16) | (unsigned)(src[i] & 0xFFFF);
            }
        }
        return;
    }

    // ---- t1 path ----
    int bid = blockIdx.x - SCB;
    int wave = tid >> 6;
    int lane = tid & 63;
    int l15 = lane & 15, quad = lane >> 4;
    int M0 = (bid * 4 + wave) * 16;
    if (M0 >= N) return;                       // wave-uniform condition
    int rlim = N - M0;                         // rows valid in this tile (<=16)

    short* myl = lds[wave];
    const float* hb = h + (size_t)M0 * 256;
    #pragma unroll
    for (int r = 0; r < 16; ++r) {
        if (r < rlim) {
            float4 v = *(const float4*)&hb[(size_t)r * 256 + lane * 4];
            int2 sv; sv.x = f2bf_pk(v.x, v.y); sv.y = f2bf_pk(v.z, v.w);
            *(int2*)&myl[r * LROW + lane * 4] = sv;
        }
    }

    f32x4 acc[4];
    #pragma unroll
    for (int nt = 0; nt < 4; ++nt) acc[nt] = (f32x4){0.f, 0.f, 0.f, 0.f};

    const short* wq = wb + quad * 8;
    #pragma unroll
    for (int kc = 0; kc < 256; kc += 32) {
        bf16x8 af = *(const bf16x8*)&myl[l15 * LROW + kc + quad * 8];
        #pragma unroll
        for (int nt = 0; nt < 4; ++nt) {
            bf16x8 bf = *(const bf16x8*)(wq + (size_t)(nt * 16 + l15) * 256 + kc);
            acc[nt] = __builtin_amdgcn_mfma_f32_16x16x32_bf16(af, bf, acc[nt], 0, 0, 0);
        }
    }

    float pa[4] = {0.f, 0.f, 0.f, 0.f};
    float pb[4] = {0.f, 0.f, 0.f, 0.f};
    #pragma unroll
    for (int nt = 0; nt < 4; ++nt) {
        int n = nt * 16 + l15;
        float bias = t1b[n];
        float gd = gw[n], gs = gw[64 + n];
        #pragma unroll
        for (int r = 0; r < 4; ++r) {
            int row = quad * 4 + r;
            if (row < rlim) {
                float x = fmaxf(acc[nt][r] + bias, 0.f);
                XAh[(size_t)(M0 + row) * 64 + n] = f2bf(x);
                pa[r] += x * gd;
                pb[r] += x * gs;
            }
        }
    }
    #pragma unroll
    for (int off = 1; off < 16; off <<= 1) {
        #pragma unroll
        for (int r = 0; r < 4; ++r) {
            pa[r] += __shfl_xor(pa[r], off, 64);
            pb[r] += __shfl_xor(pb[r], off, 64);
        }
    }
    if (l15 == 0) {
        #pragma unroll
        for (int r = 0; r < 4; ++r) {
            int row = quad * 4 + r;
            if (row < rlim) {
                ga0[M0 + row] = pa[r];
                gb0[M0 + row] = pb[r];
            }
        }
    }
}

// Gather core v3 (R18): bucket rows (fixed stride CAP), deg from cnt[],
// d = rsqrt(deg) computed inline. 2 nodes/wave (32 lanes each), 4 edge
// groups x 8 feature lanes; per-edge coefficient computed ONCE in the
// fully-active preamble and distributed via bpermute. All __shfl sites are
// fully active (R13 discipline); guards wrap only loads/FMA.
__device__ __forceinline__ void gather_core3(
    const int* __restrict__ cnt, const unsigned short* __restrict__ esrc2,
    const float* __restrict__ a, const float* __restrict__ gb,
    const unsigned* __restrict__ spill, const int* __restrict__ spillN,
    const short* __restrict__ xch, const short* __restrict__ rawh,
    float gbias, int t, int lane, float acc[8])
{
    int g = (lane >> 3) & 3;  // edge group 0..3 within this node's half
    int l = lane & 7;         // feature octet
    int j = lane & 31;        // lane index within node half
    int hbase = lane & 32;    // shfl base of this half

    int deg = cnt[t];
    int degrow = min(deg, CAP);
    int beg = t * CAP;
    float atg = a[t] + gbias;
    float dt = rsqrtf(fmaxf((float)deg, 1.0f));

    // preload up to 32 edges; one coefficient per edge (single tanh)
    int ev = (j < degrow) ? (int)esrc2[beg + j] : 0;
    float gbe = gb[ev];
    float ce = (float)cnt[ev];
    float cv = fast_tanh(atg + gbe) * dt * rsqrtf(fmaxf(ce, 1.0f));

    // distribute: group g's k-th edge lives on preload lane hbase + g + 4k
    int sarr[8]; float carr[8];
    #pragma unroll
    for (int k = 0; k < 8; ++k) {
        int srcl = hbase + g + 4 * k;
        sarr[k] = __shfl(ev, srcl, 64);
        carr[k] = __shfl(cv, srcl, 64);
    }

    #pragma unroll
    for (int k = 0; k < 8; ++k) acc[k] = 0.f;
    if (g == 0) {
        bf16x8 rv = *(const bf16x8*)&rawh[(size_t)t * 64 + l * 8];
        #pragma unroll
        for (int k = 0; k < 8; ++k) acc[k] = EPS * bf2f(rv[k]);
    }

    int lim = min(degrow, 32);
    #pragma unroll
    for (int k = 0; k < 8; ++k) {
        if (g + 4 * k < lim) {
            int s0 = sarr[k];
            float c0 = carr[k];
            bf16x8 x0 = *(const bf16x8*)&xch[(size_t)s0 * 64 + l * 8];
            #pragma unroll
            for (int kk = 0; kk < 8; ++kk) acc[kk] += c0 * bf2f(x0[kk]);
        }
    }
    // mid tail: slots 32..degrow (Poisson(16): P(deg>32) ~ 1.1e-4)
    for (int i = beg + 32 + g; i < beg + degrow; i += 4) {
        int s0 = (int)esrc2[i];
        float c0 = fast_tanh(atg + gb[s0]) * dt * rsqrtf(fmaxf((float)cnt[s0], 1.f));
        bf16x8 x0 = *(const bf16x8*)&xch[(size_t)s0 * 64 + l * 8];
        #pragma unroll
        for (int k = 0; k < 8; ++k) acc[k] += c0 * bf2f(x0[k]);
    }
    // spill list (deg > CAP; essentially never on this input)
    int sn = min(*spillN, SPILLCAP);
    if (sn > 0) {
        for (int i = 0; i < sn; ++i) {
            unsigned e = spill[i];
            if ((int)(e >> 16) == t && g == 0) {
                int s0 = (int)(e & 0xFFFFu);
                float c0 = fast_tanh(atg + gb[s0]) * dt * rsqrtf(fmaxf((float)cnt[s0], 1.f));
                bf16x8 x0 = *(const bf16x8*)&xch[(size_t)s0 * 64 + l * 8];
                #pragma unroll
                for (int k = 0; k < 8; ++k) acc[k] += c0 * bf2f(x0[k]);
            }
        }
    }

    // reduce across the 4 edge groups (bits 3,4 of lane; stays within half)
    #pragma unroll
    for (int off = 8; off < 32; off <<= 1) {
        #pragma unroll
        for (int k = 0; k < 8; ++k) acc[k] += __shfl_xor(acc[k], off, 64);
    }
}

// layer 0: x1(bf16) = EPS*x0 + gather(x0); next-layer gate dots (ga1, gb1)
__global__ __launch_bounds__(256) void gather_mid(
    const int* __restrict__ cnt, const unsigned short* __restrict__ esrc2,
    const float* __restrict__ a, const float* __restrict__ gb,
    const unsigned* __restrict__ spill, const int* __restrict__ spillN,
    const short* __restrict__ xch, const float* __restrict__ gbp,
    short* __restrict__ xnh, const float* __restrict__ gw_next,
    float* __restrict__ ga_next, float* __restrict__ gb_next, int N)
{
    int tid = threadIdx.x;
    int t = blockIdx.x * 8 + (tid >> 5);
    int tt = min(t, N - 1);               // clamp: keep all 64 lanes active
    bool valid = (t < N);
    int lane = tid & 63;
    int g = (lane >> 3) & 3, l = lane & 7;
    float acc[8];
    gather_core3(cnt, esrc2, a, gb, spill, spillN, xch, xch, gbp[0], tt, lane, acc);

    if (g == 0 && valid) {
        int4 o;
        o.x = f2bf_pk(acc[0], acc[1]); o.y = f2bf_pk(acc[2], acc[3]);
        o.z = f2bf_pk(acc[4], acc[5]); o.w = f2bf_pk(acc[6], acc[7]);
        *(int4*)&xnh[(size_t)tt * 64 + l * 8] = o;
    }
    float av = 0.f, bv = 0.f;
    #pragma unroll
    for (int k = 0; k < 8; ++k) {
        av += acc[k] * gw_next[l * 8 + k];
        bv += acc[k] * gw_next[64 + l * 8 + k];
    }
    #pragma unroll
    for (int off = 1; off < 8; off <<= 1) {
        av += __shfl_xor(av, off, 64);
        bv += __shfl_xor(bv, off, 64);
    }
    if ((lane & 31) == 0 && valid) {
        ga_next[tt] = av;
        gb_next[tt] = bv;
    }
}

// layer 1: fused gather + t2 matmul + log_softmax; x2 never materialized.
__global__ __launch_bounds__(256) void gather_out(
    const int* __restrict__ cnt, const unsigned short* __restrict__ esrc2,
    const float* __restrict__ a, const float* __restrict__ gb,
    const unsigned* __restrict__ spill, const int* __restrict__ spillN,
    const short* __restrict__ xch, const short* __restrict__ rawh,
    const float* __restrict__ gbp, const float* __restrict__ t2w,
    const float* __restrict__ t2b, float* __restrict__ out, int N)
{
    int tid = threadIdx.x;
    int t = blockIdx.x * 8 + (tid >> 5);
    int tt = min(t, N - 1);
    bool valid = (t < N);
    int lane = tid & 63;
    int g = (lane >> 3) & 3, l = lane & 7;
    float acc[8];
    gather_core3(cnt, esrc2, a, gb, spill, spillN, xch, rawh, gbp[1], tt, lane, acc);

    // 4 outputs per edge-group: j0..j0+3 of 16
    int j0 = 4 * g;
    float p[4];
    #pragma unroll
    for (int i = 0; i < 4; ++i) {
        const float* w = &t2w[(size_t)(j0 + i) * 64 + l * 8];
        float s = 0.f;
        #pragma unroll
        for (int k = 0; k < 8; ++k) s += acc[k] * w[k];
        p[i] = s;
    }
    #pragma unroll
    for (int off = 1; off < 8; off <<= 1) {
        #pragma unroll
        for (int i = 0; i < 4; ++i) p[i] += __shfl_xor(p[i], off, 64);
    }
    float li[4];
    #pragma unroll
    for (int i = 0; i < 4; ++i) li[i] = p[i] + t2b[j0 + i];
    float m = fmaxf(fmaxf(li[0], li[1]), fmaxf(li[2], li[3]));
    #pragma unroll
    for (int off = 8; off < 32; off <<= 1) m = fmaxf(m, __shfl_xor(m, off, 64));
    float s = 0.f;
    #pragma unroll
    for (int i = 0; i < 4; ++i) s += __expf(li[i] - m);
    #pragma unroll
    for (int off = 8; off < 32; off <<= 1) s += __shfl_xor(s, off, 64);
    float lse = m + __logf(s);
    if (l == 0 && valid) {
        float4 o;
        o.x = li[0] - lse; o.y = li[1] - lse;
        o.z = li[2] - lse; o.w = li[3] - lse;
        *(float4*)&out[(size_t)tt * 16 + j0] = o;
    }
}

extern "C" void kernel_launch(void* const* d_in, const int* in_sizes, int n_in,
                              void* d_out, int out_size, void* d_ws, size_t ws_size,
                              hipStream_t stream) {
    const float* h    = (const float*)d_in[0];
    const int*   src  = (const int*)d_in[1];
    const int*   dst  = (const int*)d_in[2];
    const float* t1w  = (const float*)d_in[3];
    const float* t1b  = (const float*)d_in[4];
    const float* gw   = (const float*)d_in[5];   // [2, 128]
    const float* gbia = (const float*)d_in[6];   // [2]
    const float* t2w  = (const float*)d_in[7];   // [16, 64]
    const float* t2b  = (const float*)d_in[8];   // [16]
    float* out = (float*)d_out;

    int N = in_sizes[0] / 256;                   // 50000 < 65536 (u16 packing)
    int E = in_sizes[1];

    char* p = (char*)d_ws;
    short*    XAh    = (short*)p;       p += (size_t)N * 64 * 2;   // x0 bf16
    short*    XBh    = (short*)p;       p += (size_t)N * 64 * 2;   // x1 bf16
    float*    ga0    = (float*)p;       p += (size_t)N * 4;
    float*    ga1    = (float*)p;       p += (size_t)N * 4;
    float*    gb0    = (float*)p;       p += (size_t)N * 4;
    float*    gb1    = (float*)p;       p += (size_t)N * 4;
    int*      cnt    = (int*)p;         p += (size_t)N * 4;
    int*      spillN = (int*)p;         p += 16;
    unsigned* spill  = (unsigned*)p;    p += (size_t)SPILLCAP * 4;
    p = (char*)(((size_t)p + 15) & ~(size_t)15);
    unsigned short* esrc2 = (unsigned short*)p; p += (size_t)N * CAP * 2;
    p = (char*)(((size_t)p + 15) & ~(size_t)15);
    short*    wbf    = (short*)p;

    // K1: w conversion + counter zeroing
    init_k<<<256, 256, 0, stream>>>(t1w, wbf, cnt, spillN, N);

    // K2: edge bucket scatter (blocks 0..SCB-1) || t1+relu MFMA (rest)
    int SCB = 240;
    scatter_t1<<<SCB + (N + 63) / 64, 256, 0, stream>>>(
        src, dst, E, cnt, esrc2, spill, spillN,
        h, wbf, t1b, gw, XAh, ga0, gb0, N, SCB);

    // K3: layer 0 gather — x1(bf16) = EPS*x0 + gather(x0); layer-1 gate dots
    gather_mid<<<(N + 7) / 8, 256, 0, stream>>>(cnt, esrc2, ga0, gb0, spill, spillN,
                                                XAh, gbia, XBh, gw + 128, ga1, gb1, N);

    // K4: layer 1 fused gather + t2 + log_softmax
    gather_out<<<(N + 7) / 8, 256, 0, stream>>>(cnt, esrc2, ga1, gb1, spill, spillN,
                                                XBh, XAh, gbia, t2w, t2b, out, N);
}